// Round 2
// baseline (2296.676 us; speedup 1.0000x reference)
//
#include <hip/hip_runtime.h>

#define N_RID  100000
#define N_CELL 400000
#define NCOLS  4
#define NE     100000
#define D      64
#define TOTE   (NCOLS * NE)          // 400000 edges per direction

// ================================================================ CSR build
__global__ void hist_kernel(const int* __restrict__ dst, int* __restrict__ cnt,
                            int ndst) {
    int t = blockIdx.x * 256 + threadIdx.x;
    if (t >= TOTE) return;
    int c = t / NE;
    atomicAdd(&cnt[c * ndst + dst[t]], 1);
}

// 3-phase exclusive scan (chunk = 1024)
__global__ void scan1(const int* __restrict__ in, int* __restrict__ out,
                      int* __restrict__ csum, int n) {
    __shared__ int lds[256];
    int base = blockIdx.x * 1024 + threadIdx.x * 4;
    int v0 = 0, v1 = 0, v2 = 0, v3 = 0;
    if (base + 0 < n) v0 = in[base + 0];
    if (base + 1 < n) v1 = in[base + 1];
    if (base + 2 < n) v2 = in[base + 2];
    if (base + 3 < n) v3 = in[base + 3];
    int tsum = v0 + v1 + v2 + v3;
    lds[threadIdx.x] = tsum;
    __syncthreads();
    for (int off = 1; off < 256; off <<= 1) {
        int x = (threadIdx.x >= off) ? lds[threadIdx.x - off] : 0;
        __syncthreads();
        lds[threadIdx.x] += x;
        __syncthreads();
    }
    int excl = lds[threadIdx.x] - tsum;
    if (base + 0 < n) out[base + 0] = excl;
    if (base + 1 < n) out[base + 1] = excl + v0;
    if (base + 2 < n) out[base + 2] = excl + v0 + v1;
    if (base + 3 < n) out[base + 3] = excl + v0 + v1 + v2;
    if (threadIdx.x == 255) csum[blockIdx.x] = lds[255];
}

__global__ void scan2(int* __restrict__ a, int m) {   // in-place excl scan, m<=4096
    __shared__ int lds[256];
    int per = (m + 255) >> 8;
    int st = threadIdx.x * per;
    int s = 0;
    for (int i = 0; i < per; ++i) if (st + i < m) s += a[st + i];
    lds[threadIdx.x] = s;
    __syncthreads();
    for (int off = 1; off < 256; off <<= 1) {
        int x = (threadIdx.x >= off) ? lds[threadIdx.x - off] : 0;
        __syncthreads();
        lds[threadIdx.x] += x;
        __syncthreads();
    }
    int run = lds[threadIdx.x] - s;
    for (int i = 0; i < per; ++i) if (st + i < m) { int v = a[st + i]; a[st + i] = run; run += v; }
}

__global__ void scan3(int* __restrict__ out, const int* __restrict__ csum, int n) {
    int i = blockIdx.x * 256 + threadIdx.x;
    if (i < n) out[i] += csum[i >> 10];
}

// destructive fill: consumes cnt (ends at 0), writes col
__global__ void fill_kernel(const int* __restrict__ dst, const int* __restrict__ src,
                            const int* __restrict__ ptr, int* __restrict__ cnt,
                            int* __restrict__ col, int ndst) {
    int t = blockIdx.x * 256 + threadIdx.x;
    if (t >= TOTE) return;
    int c = t / NE;
    int bin = c * ndst + dst[t];
    int old = atomicSub(&cnt[bin], 1);
    col[ptr[bin] + old - 1] = src[t];
}

// ================================================== y = (h - mu) @ W_c  (4 relations)
__global__ void __launch_bounds__(256) y_gemm(const float* __restrict__ h,
        const float* __restrict__ W, const float* __restrict__ mu,
        float* __restrict__ y, int nrows) {
    __shared__ float hlds[64 * D];
    const int wave = threadIdx.x >> 6;
    const int lane = threadIdx.x & 63;
    float w[D];
#pragma unroll
    for (int k = 0; k < D; ++k) w[k] = W[(wave * D + k) * D + lane];

    int row0 = blockIdx.x * 64;
    int nr = min(64, nrows - row0);
    for (int i = threadIdx.x; i < nr * 16; i += 256) {
        int r = i >> 4, q = i & 15;
        float4 v = reinterpret_cast<const float4*>(h + (size_t)(row0 + r) * D)[q];
        if (mu) {
            float4 m = reinterpret_cast<const float4*>(mu)[q];
            v.x -= m.x; v.y -= m.y; v.z -= m.z; v.w -= m.w;
        }
        reinterpret_cast<float4*>(hlds + r * D)[q] = v;
    }
    __syncthreads();
    for (int r = 0; r < nr; ++r) {
        const float4* hr = reinterpret_cast<const float4*>(hlds + r * D);
        float a0 = 0.f, a1 = 0.f, a2 = 0.f, a3 = 0.f;
#pragma unroll
        for (int k4 = 0; k4 < 16; ++k4) {
            float4 v = hr[k4];
            a0 = fmaf(v.x, w[4 * k4 + 0], a0);
            a1 = fmaf(v.y, w[4 * k4 + 1], a1);
            a2 = fmaf(v.z, w[4 * k4 + 2], a2);
            a3 = fmaf(v.w, w[4 * k4 + 3], a3);
        }
        y[((size_t)wave * nrows + row0 + r) * D + lane] = (a0 + a1) + (a2 + a3);
    }
}

// ============ cell: out[n] = bbar + 0.25*sum_c sc_c(n)*( sum_e y_c[src_e] + (h[n]-mu)@W_c )
#define TILE_C 16
__global__ void __launch_bounds__(256) cell_fused(const float* __restrict__ h,
        const float* __restrict__ y, const int* __restrict__ ptr,
        const int* __restrict__ col, const float* __restrict__ W,
        const float* __restrict__ bias, const float* __restrict__ mu,
        float* __restrict__ out) {
    __shared__ float hlds[TILE_C * D];
    __shared__ float part[4][TILE_C * D];
    __shared__ float sc[4][TILE_C];
    const int wave = threadIdx.x >> 6;
    const int lane = threadIdx.x & 63;
    int row0 = blockIdx.x * TILE_C;           // N_CELL % TILE_C == 0

    for (int i = threadIdx.x; i < TILE_C * 16; i += 256) {
        int r = i >> 4, q = i & 15;
        float4 v = reinterpret_cast<const float4*>(h + (size_t)(row0 + r) * D)[q];
        if (mu) {
            float4 m = reinterpret_cast<const float4*>(mu)[q];
            v.x -= m.x; v.y -= m.y; v.z -= m.z; v.w -= m.w;
        }
        reinterpret_cast<float4*>(hlds + r * D)[q] = v;
    }
    float w[D];
#pragma unroll
    for (int k = 0; k < D; ++k) w[k] = W[(wave * D + k) * D + lane];

    // gather phase (output space): part[wave][r] = sum_e y_c[src_e]
    for (int r = 0; r < TILE_C; ++r) {
        int bin = wave * N_CELL + row0 + r;
        int p0 = ptr[bin];
        int p1 = (bin == NCOLS * N_CELL - 1) ? TOTE : ptr[bin + 1];
        float g = 0.f;
        for (int e = p0; e < p1; ++e) {
            int s = col[e];
            g += y[((size_t)wave * N_RID + s) * D + lane];
        }
        part[wave][r * D + lane] = g;
        if (lane == 0) sc[wave][r] = 1.0f / (float)(p1 - p0 + 1);
    }
    __syncthreads();
    // dot phase: 4 independent FMA chains
    for (int r = 0; r < TILE_C; ++r) {
        const float4* hr = reinterpret_cast<const float4*>(hlds + r * D);
        float a0 = 0.f, a1 = 0.f, a2 = 0.f, a3 = 0.f;
#pragma unroll
        for (int k4 = 0; k4 < 16; ++k4) {
            float4 v = hr[k4];
            a0 = fmaf(v.x, w[4 * k4 + 0], a0);
            a1 = fmaf(v.y, w[4 * k4 + 1], a1);
            a2 = fmaf(v.z, w[4 * k4 + 2], a2);
            a3 = fmaf(v.w, w[4 * k4 + 3], a3);
        }
        part[wave][r * D + lane] =
            sc[wave][r] * (part[wave][r * D + lane] + ((a0 + a1) + (a2 + a3)));
    }
    __syncthreads();
    for (int i = threadIdx.x; i < TILE_C * D; i += 256) {
        int j = i & 63;
        float b = 0.25f * (bias[j] + bias[64 + j] + bias[128 + j] + bias[192 + j]);
        out[(size_t)row0 * D + i] =
            0.25f * (part[0][i] + part[1][i] + part[2][i] + part[3][i]) + b;
    }
}

// ===== rid: out[n] = bbar + 0.25*sum_c sc_c(n)*( (sum_e hs[src_e] - dg*mu_s + h[n]-mu_d) @ W_c )
#define TILE_R 16
__global__ void __launch_bounds__(256) rid_fused(const float* __restrict__ h,
        const float* __restrict__ hs, const int* __restrict__ ptr,
        const int* __restrict__ col, const float* __restrict__ W,
        const float* __restrict__ bias, const float* __restrict__ mu_d,
        const float* __restrict__ mu_s, float* __restrict__ out) {
    __shared__ float hlds[TILE_R * D];
    __shared__ float buf[4][TILE_R * D];      // agg (k-space), then z (j-space)
    __shared__ float sc[4][TILE_R];
    const int wave = threadIdx.x >> 6;
    const int lane = threadIdx.x & 63;
    int row0 = blockIdx.x * TILE_R;           // N_RID % TILE_R == 0

    for (int i = threadIdx.x; i < TILE_R * 16; i += 256) {
        int r = i >> 4, q = i & 15;
        float4 v = reinterpret_cast<const float4*>(h + (size_t)(row0 + r) * D)[q];
        if (mu_d) {
            float4 m = reinterpret_cast<const float4*>(mu_d)[q];
            v.x -= m.x; v.y -= m.y; v.z -= m.z; v.w -= m.w;
        }
        reinterpret_cast<float4*>(hlds + r * D)[q] = v;
    }
    float muk = mu_s ? mu_s[lane] : 0.f;
    float w[D];
#pragma unroll
    for (int k = 0; k < D; ++k) w[k] = W[(wave * D + k) * D + lane];

    // gather phase (input space): buf[wave][r][k] = sum_e hs[src_e][k] - dg*mu_s[k]
    for (int r = 0; r < TILE_R; ++r) {
        int bin = wave * N_RID + row0 + r;
        int p0 = ptr[bin];
        int p1 = (bin == NCOLS * N_RID - 1) ? TOTE : ptr[bin + 1];
        float g = 0.f;
        for (int e = p0; e < p1; ++e) {
            int s = col[e];
            g += hs[(size_t)s * D + lane];
        }
        buf[wave][r * D + lane] = g - (float)(p1 - p0) * muk;
        if (lane == 0) sc[wave][r] = 1.0f / (float)(p1 - p0 + 1);
    }
    __syncthreads();
    for (int r = 0; r < TILE_R; ++r) {
        const float4* hr = reinterpret_cast<const float4*>(hlds + r * D);
        const float4* ar = reinterpret_cast<const float4*>(buf[wave] + r * D);
        float a0 = 0.f, a1 = 0.f, a2 = 0.f, a3 = 0.f;
#pragma unroll
        for (int k4 = 0; k4 < 16; ++k4) {
            float4 v = hr[k4];
            float4 a = ar[k4];
            a0 = fmaf(v.x + a.x, w[4 * k4 + 0], a0);
            a1 = fmaf(v.y + a.y, w[4 * k4 + 1], a1);
            a2 = fmaf(v.z + a.z, w[4 * k4 + 2], a2);
            a3 = fmaf(v.w + a.w, w[4 * k4 + 3], a3);
        }
        float z = sc[wave][r] * ((a0 + a1) + (a2 + a3));
        buf[wave][r * D + lane] = z;          // wave-synchronous: reads precede write
    }
    __syncthreads();
    for (int i = threadIdx.x; i < TILE_R * D; i += 256) {
        int j = i & 63;
        float b = 0.25f * (bias[j] + bias[64 + j] + bias[128 + j] + bias[192 + j]);
        out[(size_t)row0 * D + i] =
            0.25f * (buf[0][i] + buf[1][i] + buf[2][i] + buf[3][i]) + b;
    }
}

// ------------------------- column sums (for centering)
__global__ void colsum(const float* __restrict__ x, float* __restrict__ sum, int nrows) {
    __shared__ float p[4][64];
    int j = threadIdx.x & 63, rl = threadIdx.x >> 6;
    float local = 0.f;
    for (int r = blockIdx.x * 4 + rl; r < nrows; r += gridDim.x * 4)
        local += x[(size_t)r * D + j];
    p[rl][j] = local;
    __syncthreads();
    if (rl == 0) atomicAdd(&sum[j], p[0][j] + p[1][j] + p[2][j] + p[3][j]);
}

__global__ void finalize_mean(float* __restrict__ s, float inv_n) {
    s[threadIdx.x] *= inv_n;
}

// ------------------------- combine + center + relu (in place on out)
__global__ void final_combine(float* __restrict__ out, const float* __restrict__ rid,
        const float* __restrict__ mu_c, const float* __restrict__ mu_r) {
    int t = blockIdx.x * 256 + threadIdx.x;
    if (t >= N_CELL * D) return;
    int row = t >> 6, j = t & 63;
    float v = (row < N_RID) ? (rid[(size_t)row * D + j] - mu_r[j])
                            : (out[t] - mu_c[j]);
    out[t] = fmaxf(v, 0.0f);
}

extern "C" void kernel_launch(void* const* d_in, const int* in_sizes, int n_in,
                              void* d_out, int out_size, void* d_ws, size_t ws_size,
                              hipStream_t stream) {
    const float* x_rid  = (const float*)d_in[0];
    const float* x_cell = (const float*)d_in[1];
    const int* src_fwd  = (const int*)d_in[2];
    const int* dst_fwd  = (const int*)d_in[3];
    const int* src_rev  = (const int*)d_in[4];
    const int* dst_rev  = (const int*)d_in[5];
    const float* W1f = (const float*)d_in[6];
    const float* b1f = (const float*)d_in[7];
    const float* W1r = (const float*)d_in[8];
    const float* b1r = (const float*)d_in[9];
    const float* W2f = (const float*)d_in[10];
    const float* b2f = (const float*)d_in[11];
    const float* W2r = (const float*)d_in[12];
    const float* b2r = (const float*)d_in[13];
    float* out = (float*)d_out;

    float* ws    = (float*)d_ws;
    float* rid1  = ws;                                   //  6.4M f32
    float* cell1 = rid1  + (size_t)N_RID * D;            // 25.6M
    float* rid2  = cell1 + (size_t)N_CELL * D;           //  6.4M (overlaid in build)
    float* y     = rid2  + (size_t)N_RID * D;            // 25.6M
    float* sums  = y     + (size_t)NCOLS * N_RID * D;    //  256
    int*   ptrF  = (int*)(sums + 256);                   //  1.6M int
    int*   colF  = ptrF + (size_t)NCOLS * N_CELL;        //  0.4M
    int*   ptrR  = colF + TOTE;                          //  0.4M
    int*   colR  = ptrR + (size_t)NCOLS * N_RID;         //  0.4M
    // build-phase overlays inside rid2 region (8.02 MB < 25.6 MB; dead by layer 2)
    int*   cntF  = (int*)rid2;                           //  1.6M int
    int*   cntR  = cntF + (size_t)NCOLS * N_CELL;        //  0.4M
    int*   csumF = cntR + (size_t)NCOLS * N_RID;         //  2048
    int*   csumR = csumF + 2048;                         //  2048

    const int NBF = NCOLS * N_CELL;     // 1.6M bins
    const int NBR = NCOLS * N_RID;      // 0.4M bins
    const int g_edges = (TOTE + 255) / 256;

    hipMemsetAsync(cntF, 0, (size_t)NBF * sizeof(int), stream);
    hipMemsetAsync(cntR, 0, (size_t)NBR * sizeof(int), stream);
    hipMemsetAsync(sums, 0, 256 * sizeof(float), stream);

    // ---- CSR build (used by both layers) ----
    hist_kernel<<<g_edges, 256, 0, stream>>>(dst_fwd, cntF, N_CELL);
    hist_kernel<<<g_edges, 256, 0, stream>>>(dst_rev, cntR, N_RID);
    int nchF = (NBF + 1023) / 1024, nchR = (NBR + 1023) / 1024;
    scan1<<<nchF, 256, 0, stream>>>(cntF, ptrF, csumF, NBF);
    scan2<<<1, 256, 0, stream>>>(csumF, nchF);
    scan3<<<(NBF + 255) / 256, 256, 0, stream>>>(ptrF, csumF, NBF);
    scan1<<<nchR, 256, 0, stream>>>(cntR, ptrR, csumR, NBR);
    scan2<<<1, 256, 0, stream>>>(csumR, nchR);
    scan3<<<(NBR + 255) / 256, 256, 0, stream>>>(ptrR, csumR, NBR);
    fill_kernel<<<g_edges, 256, 0, stream>>>(dst_fwd, src_fwd, ptrF, cntF, colF, N_CELL);
    fill_kernel<<<g_edges, 256, 0, stream>>>(dst_rev, src_rev, ptrR, cntR, colR, N_RID);

    // ---------------- layer 1 ----------------
    y_gemm<<<(N_RID + 63) / 64, 256, 0, stream>>>(x_rid, W1f, nullptr, y, N_RID);
    cell_fused<<<N_CELL / TILE_C, 256, 0, stream>>>(x_cell, y, ptrF, colF, W1f, b1f,
                                                    nullptr, cell1);
    rid_fused<<<N_RID / TILE_R, 256, 0, stream>>>(x_rid, x_cell, ptrR, colR, W1r, b1r,
                                                  nullptr, nullptr, rid1);
    colsum<<<1024, 256, 0, stream>>>(cell1, sums + 0, N_CELL);
    colsum<<<1024, 256, 0, stream>>>(rid1, sums + 64, N_RID);
    finalize_mean<<<1, 64, 0, stream>>>(sums + 0, 1.0f / N_CELL);
    finalize_mean<<<1, 64, 0, stream>>>(sums + 64, 1.0f / N_RID);

    // ---------------- layer 2 ----------------
    y_gemm<<<(N_RID + 63) / 64, 256, 0, stream>>>(rid1, W2f, sums + 64, y, N_RID);
    cell_fused<<<N_CELL / TILE_C, 256, 0, stream>>>(cell1, y, ptrF, colF, W2f, b2f,
                                                    sums + 0, out);
    rid_fused<<<N_RID / TILE_R, 256, 0, stream>>>(rid1, cell1, ptrR, colR, W2r, b2r,
                                                  sums + 64, sums + 0, rid2);
    colsum<<<1024, 256, 0, stream>>>(out, sums + 128, N_CELL);
    colsum<<<1024, 256, 0, stream>>>(rid2, sums + 192, N_RID);
    finalize_mean<<<1, 64, 0, stream>>>(sums + 128, 1.0f / N_CELL);
    finalize_mean<<<1, 64, 0, stream>>>(sums + 192, 1.0f / N_RID);

    final_combine<<<(N_CELL * D) / 256, 256, 0, stream>>>(out, rid2, sums + 128,
                                                          sums + 192);
}

// Round 3
// 2029.869 us; speedup vs baseline: 1.1314x; 1.1314x over previous
//
#include <hip/hip_runtime.h>

#define N_RID  100000
#define N_CELL 400000
#define NCOLS  4
#define NE     100000
#define D      64
#define TOTE   (NCOLS * NE)          // 400000 edges per direction

// ================================================================ CSR build
__global__ void hist_kernel(const int* __restrict__ dst, int* __restrict__ cnt,
                            int ndst) {
    int t = blockIdx.x * 256 + threadIdx.x;
    if (t >= TOTE) return;
    int c = t / NE;
    atomicAdd(&cnt[c * ndst + dst[t]], 1);
}

// 3-phase exclusive scan (chunk = 1024)
__global__ void scan1(const int* __restrict__ in, int* __restrict__ out,
                      int* __restrict__ csum, int n) {
    __shared__ int lds[256];
    int base = blockIdx.x * 1024 + threadIdx.x * 4;
    int v0 = 0, v1 = 0, v2 = 0, v3 = 0;
    if (base + 0 < n) v0 = in[base + 0];
    if (base + 1 < n) v1 = in[base + 1];
    if (base + 2 < n) v2 = in[base + 2];
    if (base + 3 < n) v3 = in[base + 3];
    int tsum = v0 + v1 + v2 + v3;
    lds[threadIdx.x] = tsum;
    __syncthreads();
    for (int off = 1; off < 256; off <<= 1) {
        int x = (threadIdx.x >= off) ? lds[threadIdx.x - off] : 0;
        __syncthreads();
        lds[threadIdx.x] += x;
        __syncthreads();
    }
    int excl = lds[threadIdx.x] - tsum;
    if (base + 0 < n) out[base + 0] = excl;
    if (base + 1 < n) out[base + 1] = excl + v0;
    if (base + 2 < n) out[base + 2] = excl + v0 + v1;
    if (base + 3 < n) out[base + 3] = excl + v0 + v1 + v2;
    if (threadIdx.x == 255) csum[blockIdx.x] = lds[255];
}

__global__ void scan2(int* __restrict__ a, int m) {   // in-place excl scan
    __shared__ int lds[256];
    int per = (m + 255) >> 8;
    int st = threadIdx.x * per;
    int s = 0;
    for (int i = 0; i < per; ++i) if (st + i < m) s += a[st + i];
    lds[threadIdx.x] = s;
    __syncthreads();
    for (int off = 1; off < 256; off <<= 1) {
        int x = (threadIdx.x >= off) ? lds[threadIdx.x - off] : 0;
        __syncthreads();
        lds[threadIdx.x] += x;
        __syncthreads();
    }
    int run = lds[threadIdx.x] - s;
    for (int i = 0; i < per; ++i) if (st + i < m) { int v = a[st + i]; a[st + i] = run; run += v; }
}

__global__ void scan3(int* __restrict__ out, const int* __restrict__ csum, int n) {
    int i = blockIdx.x * 256 + threadIdx.x;
    if (i < n) out[i] += csum[i >> 10];
}

__global__ void set_sentinels(int* __restrict__ pF, int* __restrict__ pR) {
    if (threadIdx.x == 0) {
        pF[NCOLS * N_CELL] = TOTE;
        pR[NCOLS * N_RID]  = TOTE;
    }
}

// destructive fill: consumes cnt (ends at 0), writes col
__global__ void fill_kernel(const int* __restrict__ dst, const int* __restrict__ src,
                            const int* __restrict__ ptr, int* __restrict__ cnt,
                            int* __restrict__ col, int ndst) {
    int t = blockIdx.x * 256 + threadIdx.x;
    if (t >= TOTE) return;
    int c = t / NE;
    int bin = c * ndst + dst[t];
    int old = atomicSub(&cnt[bin], 1);
    col[ptr[bin] + old - 1] = src[t];
}

// ================================================== y = (h - mu) @ W_c  (4 relations)
__global__ void __launch_bounds__(256) y_gemm(const float* __restrict__ h,
        const float* __restrict__ W, const float* __restrict__ mu,
        float* __restrict__ y, int nrows) {
    __shared__ float hlds[64 * D];
    const int wave = threadIdx.x >> 6;
    const int lane = threadIdx.x & 63;
    float w[D];
#pragma unroll
    for (int k = 0; k < D; ++k) w[k] = W[(wave * D + k) * D + lane];

    int row0 = blockIdx.x * 64;
    int nr = min(64, nrows - row0);
    for (int i = threadIdx.x; i < nr * 16; i += 256) {
        int r = i >> 4, q = i & 15;
        float4 v = reinterpret_cast<const float4*>(h + (size_t)(row0 + r) * D)[q];
        if (mu) {
            float4 m = reinterpret_cast<const float4*>(mu)[q];
            v.x -= m.x; v.y -= m.y; v.z -= m.z; v.w -= m.w;
        }
        reinterpret_cast<float4*>(hlds + r * D)[q] = v;
    }
    __syncthreads();
    for (int r = 0; r < nr; ++r) {
        const float4* hr = reinterpret_cast<const float4*>(hlds + r * D);
        float a0 = 0.f, a1 = 0.f, a2 = 0.f, a3 = 0.f;
#pragma unroll
        for (int k4 = 0; k4 < 16; ++k4) {
            float4 v = hr[k4];
            a0 = fmaf(v.x, w[4 * k4 + 0], a0);
            a1 = fmaf(v.y, w[4 * k4 + 1], a1);
            a2 = fmaf(v.z, w[4 * k4 + 2], a2);
            a3 = fmaf(v.w, w[4 * k4 + 3], a3);
        }
        y[((size_t)wave * nrows + row0 + r) * D + lane] = (a0 + a1) + (a2 + a3);
    }
}

// ============ cell: out[n] = bbar + 0.25*sum_c sc_c(n)*( sum_e y_c[src_e] + (h[n]-mu)@W_c )
#define TILE_C 16
__global__ void __launch_bounds__(256) cell_fused(const float* __restrict__ h,
        const float* __restrict__ y, const int* __restrict__ ptr,
        const int* __restrict__ col, const float* __restrict__ W,
        const float* __restrict__ bias, const float* __restrict__ mu,
        float* __restrict__ out) {
    __shared__ float hlds[TILE_C * D];
    __shared__ float part[4][TILE_C * D];
    __shared__ int pl[4][TILE_C + 1];
    __shared__ float sc[4][TILE_C];
    const int wave = threadIdx.x >> 6;
    const int lane = threadIdx.x & 63;
    int row0 = blockIdx.x * TILE_C;           // N_CELL % TILE_C == 0

    // cooperative coalesced ptr prefetch (sentinel array: ptr[NB] valid)
    if (threadIdx.x < 4 * (TILE_C + 1)) {
        int c = threadIdx.x / (TILE_C + 1), i = threadIdx.x % (TILE_C + 1);
        pl[c][i] = ptr[(size_t)c * N_CELL + row0 + i];
    }
    for (int i = threadIdx.x; i < TILE_C * 16; i += 256) {
        int r = i >> 4, q = i & 15;
        float4 v = reinterpret_cast<const float4*>(h + (size_t)(row0 + r) * D)[q];
        if (mu) {
            float4 m = reinterpret_cast<const float4*>(mu)[q];
            v.x -= m.x; v.y -= m.y; v.z -= m.z; v.w -= m.w;
        }
        reinterpret_cast<float4*>(hlds + r * D)[q] = v;
    }
    float w[D];
#pragma unroll
    for (int k = 0; k < D; ++k) w[k] = W[(wave * D + k) * D + lane];
    __syncthreads();

    // gather phase (output space): part[wave][r] = sum_e y_c[src_e]
    for (int r = 0; r < TILE_C; ++r) {
        int p0 = pl[wave][r], p1 = pl[wave][r + 1];
        float g = 0.f;
        for (int e = p0; e < p1; ++e)
            g += y[((size_t)wave * N_RID + col[e]) * D + lane];
        part[wave][r * D + lane] = g;
        if (lane == 0) sc[wave][r] = 1.0f / (float)(p1 - p0 + 1);
    }
    // dot phase: 4 independent FMA chains
    for (int r = 0; r < TILE_C; ++r) {
        const float4* hr = reinterpret_cast<const float4*>(hlds + r * D);
        float a0 = 0.f, a1 = 0.f, a2 = 0.f, a3 = 0.f;
#pragma unroll
        for (int k4 = 0; k4 < 16; ++k4) {
            float4 v = hr[k4];
            a0 = fmaf(v.x, w[4 * k4 + 0], a0);
            a1 = fmaf(v.y, w[4 * k4 + 1], a1);
            a2 = fmaf(v.z, w[4 * k4 + 2], a2);
            a3 = fmaf(v.w, w[4 * k4 + 3], a3);
        }
        part[wave][r * D + lane] =
            sc[wave][r] * (part[wave][r * D + lane] + ((a0 + a1) + (a2 + a3)));
    }
    __syncthreads();
    for (int i = threadIdx.x; i < TILE_C * D; i += 256) {
        int j = i & 63;
        float b = 0.25f * (bias[j] + bias[64 + j] + bias[128 + j] + bias[192 + j]);
        out[(size_t)row0 * D + i] =
            0.25f * (part[0][i] + part[1][i] + part[2][i] + part[3][i]) + b;
    }
}

// ===== rid: out[n] = bbar + 0.25*sum_c sc_c(n)*( (sum_e hs[src_e] - dg*mu_s + h[n]-mu_d) @ W_c )
#define TILE_R 16
__global__ void __launch_bounds__(256) rid_fused(const float* __restrict__ h,
        const float* __restrict__ hs, const int* __restrict__ ptr,
        const int* __restrict__ col, const float* __restrict__ W,
        const float* __restrict__ bias, const float* __restrict__ mu_d,
        const float* __restrict__ mu_s, float* __restrict__ out) {
    __shared__ float hlds[TILE_R * D];
    __shared__ float buf[4][TILE_R * D];      // agg (k-space), then z (j-space)
    __shared__ int pl[4][TILE_R + 1];
    __shared__ float sc[4][TILE_R];
    const int wave = threadIdx.x >> 6;
    const int lane = threadIdx.x & 63;
    int row0 = blockIdx.x * TILE_R;           // N_RID % TILE_R == 0

    if (threadIdx.x < 4 * (TILE_R + 1)) {
        int c = threadIdx.x / (TILE_R + 1), i = threadIdx.x % (TILE_R + 1);
        pl[c][i] = ptr[(size_t)c * N_RID + row0 + i];
    }
    for (int i = threadIdx.x; i < TILE_R * 16; i += 256) {
        int r = i >> 4, q = i & 15;
        float4 v = reinterpret_cast<const float4*>(h + (size_t)(row0 + r) * D)[q];
        if (mu_d) {
            float4 m = reinterpret_cast<const float4*>(mu_d)[q];
            v.x -= m.x; v.y -= m.y; v.z -= m.z; v.w -= m.w;
        }
        reinterpret_cast<float4*>(hlds + r * D)[q] = v;
    }
    float muk = mu_s ? mu_s[lane] : 0.f;
    float w[D];
#pragma unroll
    for (int k = 0; k < D; ++k) w[k] = W[(wave * D + k) * D + lane];
    __syncthreads();

    // gather phase (input space): buf[wave][r][k] = sum_e hs[src_e][k] - dg*mu_s[k]
    for (int r = 0; r < TILE_R; ++r) {
        int p0 = pl[wave][r], p1 = pl[wave][r + 1];
        float g = 0.f;
        for (int e = p0; e < p1; ++e)
            g += hs[(size_t)col[e] * D + lane];
        buf[wave][r * D + lane] = g - (float)(p1 - p0) * muk;
        if (lane == 0) sc[wave][r] = 1.0f / (float)(p1 - p0 + 1);
    }
    for (int r = 0; r < TILE_R; ++r) {
        const float4* hr = reinterpret_cast<const float4*>(hlds + r * D);
        const float4* ar = reinterpret_cast<const float4*>(buf[wave] + r * D);
        float a0 = 0.f, a1 = 0.f, a2 = 0.f, a3 = 0.f;
#pragma unroll
        for (int k4 = 0; k4 < 16; ++k4) {
            float4 v = hr[k4];
            float4 a = ar[k4];
            a0 = fmaf(v.x + a.x, w[4 * k4 + 0], a0);
            a1 = fmaf(v.y + a.y, w[4 * k4 + 1], a1);
            a2 = fmaf(v.z + a.z, w[4 * k4 + 2], a2);
            a3 = fmaf(v.w + a.w, w[4 * k4 + 3], a3);
        }
        float z = sc[wave][r] * ((a0 + a1) + (a2 + a3));
        buf[wave][r * D + lane] = z;          // wave-synchronous: reads precede write
    }
    __syncthreads();
    for (int i = threadIdx.x; i < TILE_R * D; i += 256) {
        int j = i & 63;
        float b = 0.25f * (bias[j] + bias[64 + j] + bias[128 + j] + bias[192 + j]);
        out[(size_t)row0 * D + i] =
            0.25f * (buf[0][i] + buf[1][i] + buf[2][i] + buf[3][i]) + b;
    }
}

// ------------------------- column sums (for centering)
__global__ void colsum(const float* __restrict__ x, float* __restrict__ sum, int nrows) {
    __shared__ float p[4][64];
    int j = threadIdx.x & 63, rl = threadIdx.x >> 6;
    float local = 0.f;
    for (int r = blockIdx.x * 4 + rl; r < nrows; r += gridDim.x * 4)
        local += x[(size_t)r * D + j];
    p[rl][j] = local;
    __syncthreads();
    if (rl == 0) atomicAdd(&sum[j], p[0][j] + p[1][j] + p[2][j] + p[3][j]);
}

__global__ void finalize_mean(float* __restrict__ s, float inv_n) {
    s[threadIdx.x] *= inv_n;
}

// ------------------------- combine + center + relu (in place on out)
__global__ void final_combine(float* __restrict__ out, const float* __restrict__ rid,
        const float* __restrict__ mu_c, const float* __restrict__ mu_r) {
    int t = blockIdx.x * 256 + threadIdx.x;
    if (t >= N_CELL * D) return;
    int row = t >> 6, j = t & 63;
    float v = (row < N_RID) ? (rid[(size_t)row * D + j] - mu_r[j])
                            : (out[t] - mu_c[j]);
    out[t] = fmaxf(v, 0.0f);
}

extern "C" void kernel_launch(void* const* d_in, const int* in_sizes, int n_in,
                              void* d_out, int out_size, void* d_ws, size_t ws_size,
                              hipStream_t stream) {
    const float* x_rid  = (const float*)d_in[0];
    const float* x_cell = (const float*)d_in[1];
    const int* src_fwd  = (const int*)d_in[2];
    const int* dst_fwd  = (const int*)d_in[3];
    const int* src_rev  = (const int*)d_in[4];
    const int* dst_rev  = (const int*)d_in[5];
    const float* W1f = (const float*)d_in[6];
    const float* b1f = (const float*)d_in[7];
    const float* W1r = (const float*)d_in[8];
    const float* b1r = (const float*)d_in[9];
    const float* W2f = (const float*)d_in[10];
    const float* b2f = (const float*)d_in[11];
    const float* W2r = (const float*)d_in[12];
    const float* b2r = (const float*)d_in[13];
    float* out = (float*)d_out;

    float* ws    = (float*)d_ws;
    float* rid1  = ws;                                   //  6.4M f32
    float* cell1 = rid1  + (size_t)N_RID * D;            // 25.6M
    float* rid2  = cell1 + (size_t)N_CELL * D;           //  6.4M (overlaid in build)
    float* y     = rid2  + (size_t)N_RID * D;            // 25.6M
    float* sums  = y     + (size_t)NCOLS * N_RID * D;    //  256
    int*   ptrF  = (int*)(sums + 256);                   //  1.6M+1 int
    int*   colF  = ptrF + (size_t)NCOLS * N_CELL + 1;    //  0.4M
    int*   ptrR  = colF + TOTE;                          //  0.4M+1
    int*   colR  = ptrR + (size_t)NCOLS * N_RID + 1;     //  0.4M
    // build-phase overlays inside rid2 region (8.02 MB < 25.6 MB; dead by layer 2)
    int*   cntF  = (int*)rid2;                           //  1.6M int
    int*   cntR  = cntF + (size_t)NCOLS * N_CELL;        //  0.4M
    int*   csumF = cntR + (size_t)NCOLS * N_RID;         //  2048
    int*   csumR = csumF + 2048;                         //  2048

    const int NBF = NCOLS * N_CELL;     // 1.6M bins
    const int NBR = NCOLS * N_RID;      // 0.4M bins
    const int g_edges = (TOTE + 255) / 256;

    hipMemsetAsync(cntF, 0, (size_t)NBF * sizeof(int), stream);
    hipMemsetAsync(cntR, 0, (size_t)NBR * sizeof(int), stream);
    hipMemsetAsync(sums, 0, 256 * sizeof(float), stream);

    // ---- CSR build (used by both layers) ----
    hist_kernel<<<g_edges, 256, 0, stream>>>(dst_fwd, cntF, N_CELL);
    hist_kernel<<<g_edges, 256, 0, stream>>>(dst_rev, cntR, N_RID);
    int nchF = (NBF + 1023) / 1024, nchR = (NBR + 1023) / 1024;
    scan1<<<nchF, 256, 0, stream>>>(cntF, ptrF, csumF, NBF);
    scan2<<<1, 256, 0, stream>>>(csumF, nchF);
    scan3<<<(NBF + 255) / 256, 256, 0, stream>>>(ptrF, csumF, NBF);
    scan1<<<nchR, 256, 0, stream>>>(cntR, ptrR, csumR, NBR);
    scan2<<<1, 256, 0, stream>>>(csumR, nchR);
    scan3<<<(NBR + 255) / 256, 256, 0, stream>>>(ptrR, csumR, NBR);
    set_sentinels<<<1, 64, 0, stream>>>(ptrF, ptrR);
    fill_kernel<<<g_edges, 256, 0, stream>>>(dst_fwd, src_fwd, ptrF, cntF, colF, N_CELL);
    fill_kernel<<<g_edges, 256, 0, stream>>>(dst_rev, src_rev, ptrR, cntR, colR, N_RID);

    // ---------------- layer 1 ----------------
    y_gemm<<<(N_RID + 63) / 64, 256, 0, stream>>>(x_rid, W1f, nullptr, y, N_RID);
    cell_fused<<<N_CELL / TILE_C, 256, 0, stream>>>(x_cell, y, ptrF, colF, W1f, b1f,
                                                    nullptr, cell1);
    rid_fused<<<N_RID / TILE_R, 256, 0, stream>>>(x_rid, x_cell, ptrR, colR, W1r, b1r,
                                                  nullptr, nullptr, rid1);
    colsum<<<1024, 256, 0, stream>>>(cell1, sums + 0, N_CELL);
    colsum<<<1024, 256, 0, stream>>>(rid1, sums + 64, N_RID);
    finalize_mean<<<1, 64, 0, stream>>>(sums + 0, 1.0f / N_CELL);
    finalize_mean<<<1, 64, 0, stream>>>(sums + 64, 1.0f / N_RID);

    // ---------------- layer 2 ----------------
    y_gemm<<<(N_RID + 63) / 64, 256, 0, stream>>>(rid1, W2f, sums + 64, y, N_RID);
    cell_fused<<<N_CELL / TILE_C, 256, 0, stream>>>(cell1, y, ptrF, colF, W2f, b2f,
                                                    sums + 0, out);
    rid_fused<<<N_RID / TILE_R, 256, 0, stream>>>(rid1, cell1, ptrR, colR, W2r, b2r,
                                                  sums + 64, sums + 0, rid2);
    colsum<<<1024, 256, 0, stream>>>(out, sums + 128, N_CELL);
    colsum<<<1024, 256, 0, stream>>>(rid2, sums + 192, N_RID);
    finalize_mean<<<1, 64, 0, stream>>>(sums + 128, 1.0f / N_CELL);
    finalize_mean<<<1, 64, 0, stream>>>(sums + 192, 1.0f / N_RID);

    final_combine<<<(N_CELL * D) / 256, 256, 0, stream>>>(out, rid2, sums + 128,
                                                          sums + 192);
}

// Round 4
// 1048.893 us; speedup vs baseline: 2.1896x; 1.9352x over previous
//
#include <hip/hip_runtime.h>

#define N_RID  100000
#define N_CELL 400000
#define NCOLS  4
#define NE     100000
#define D      64
#define TOTE   (NCOLS * NE)          // 400000 edges per direction

typedef __attribute__((ext_vector_type(8))) short bf16x8;
typedef __attribute__((ext_vector_type(4))) float f32x4;

__device__ inline unsigned short f2bf(float f) {
    unsigned int u = __float_as_uint(f);
    return (unsigned short)((u + 0x7FFF + ((u >> 16) & 1)) >> 16);
}
__device__ inline float bf2f(unsigned short b) {
    return __uint_as_float(((unsigned int)b) << 16);
}
__device__ inline unsigned long long pack4(unsigned short a, unsigned short b,
                                           unsigned short c, unsigned short d) {
    return (unsigned long long)a | ((unsigned long long)b << 16) |
           ((unsigned long long)c << 32) | ((unsigned long long)d << 48);
}
// byte offset within a [16 rows][128B] bf16 tile, XOR-swizzled (bank-conflict fix)
__device__ inline int swz(int row, int kbyte) {
    return row * 128 + (kbyte ^ ((row & 7) << 4));
}

// ================================================================ CSR build
__global__ void hist_kernel(const int* __restrict__ dst, int* __restrict__ cnt,
                            int ndst) {
    int t = blockIdx.x * 256 + threadIdx.x;
    if (t >= TOTE) return;
    int c = t / NE;
    atomicAdd(&cnt[c * ndst + dst[t]], 1);
}

__global__ void scan1(const int* __restrict__ in, int* __restrict__ out,
                      int* __restrict__ csum, int n) {
    __shared__ int lds[256];
    int base = blockIdx.x * 1024 + threadIdx.x * 4;
    int v0 = 0, v1 = 0, v2 = 0, v3 = 0;
    if (base + 0 < n) v0 = in[base + 0];
    if (base + 1 < n) v1 = in[base + 1];
    if (base + 2 < n) v2 = in[base + 2];
    if (base + 3 < n) v3 = in[base + 3];
    int tsum = v0 + v1 + v2 + v3;
    lds[threadIdx.x] = tsum;
    __syncthreads();
    for (int off = 1; off < 256; off <<= 1) {
        int x = (threadIdx.x >= off) ? lds[threadIdx.x - off] : 0;
        __syncthreads();
        lds[threadIdx.x] += x;
        __syncthreads();
    }
    int excl = lds[threadIdx.x] - tsum;
    if (base + 0 < n) out[base + 0] = excl;
    if (base + 1 < n) out[base + 1] = excl + v0;
    if (base + 2 < n) out[base + 2] = excl + v0 + v1;
    if (base + 3 < n) out[base + 3] = excl + v0 + v1 + v2;
    if (threadIdx.x == 255) csum[blockIdx.x] = lds[255];
}

__global__ void scan2(int* __restrict__ a, int m) {
    __shared__ int lds[256];
    int per = (m + 255) >> 8;
    int st = threadIdx.x * per;
    int s = 0;
    for (int i = 0; i < per; ++i) if (st + i < m) s += a[st + i];
    lds[threadIdx.x] = s;
    __syncthreads();
    for (int off = 1; off < 256; off <<= 1) {
        int x = (threadIdx.x >= off) ? lds[threadIdx.x - off] : 0;
        __syncthreads();
        lds[threadIdx.x] += x;
        __syncthreads();
    }
    int run = lds[threadIdx.x] - s;
    for (int i = 0; i < per; ++i) if (st + i < m) { int v = a[st + i]; a[st + i] = run; run += v; }
}

__global__ void scan3(int* __restrict__ out, const int* __restrict__ csum, int n) {
    int i = blockIdx.x * 256 + threadIdx.x;
    if (i < n) out[i] += csum[i >> 10];
}

__global__ void set_sentinels(int* __restrict__ pF, int* __restrict__ pR) {
    if (threadIdx.x == 0) {
        pF[NCOLS * N_CELL] = TOTE;
        pR[NCOLS * N_RID]  = TOTE;
    }
}

__global__ void fill_kernel(const int* __restrict__ dst, const int* __restrict__ src,
                            const int* __restrict__ ptr, int* __restrict__ cnt,
                            int* __restrict__ col, int ndst) {
    int t = blockIdx.x * 256 + threadIdx.x;
    if (t >= TOTE) return;
    int c = t / NE;
    int bin = c * ndst + dst[t];
    int old = atomicSub(&cnt[bin], 1);
    col[ptr[bin] + old - 1] = src[t];
}

// ---------------- W prep: Wt[c][j][k] = bf16(W[c][k][j]) for 4 weight sets
__global__ void prep_w(const float* __restrict__ Wa, const float* __restrict__ Wb,
                       const float* __restrict__ Wc, const float* __restrict__ Wd,
                       unsigned short* __restrict__ Ta, unsigned short* __restrict__ Tb,
                       unsigned short* __restrict__ Tc, unsigned short* __restrict__ Td) {
    int t = blockIdx.x * 256 + threadIdx.x;
    if (t >= NCOLS * D * D) return;
    int c = t >> 12, jk = t & 4095, j = jk >> 6, k = jk & 63;
    int s = (c * D + k) * D + j;
    Ta[t] = f2bf(Wa[s]);
    Tb[t] = f2bf(Wb[s]);
    Tc[t] = f2bf(Wc[s]);
    Td[t] = f2bf(Wd[s]);
}

// ======================= y = (h - mu) @ W_c (MFMA, 4 relations, 16 rows/block)
__global__ void __launch_bounds__(256) y_gemm(const float* __restrict__ h,
        const unsigned short* __restrict__ Wt, const float* __restrict__ mu,
        float* __restrict__ y, int nrows) {
    __shared__ unsigned short aHi[16 * D], aLo[16 * D];
    __shared__ float part[4][16 * D];
    const int tid = threadIdx.x, c = tid >> 6, l = tid & 63;
    const int row0 = blockIdx.x * 16;

    {   // A tile build: hi/lo split bf16, swizzled
        int r = tid >> 4, c4 = tid & 15;
        float4 v = *(const float4*)(h + (size_t)(row0 + r) * D + c4 * 4);
        if (mu) {
            float4 m = ((const float4*)mu)[c4];
            v.x -= m.x; v.y -= m.y; v.z -= m.z; v.w -= m.w;
        }
        unsigned short h0 = f2bf(v.x), h1 = f2bf(v.y), h2 = f2bf(v.z), h3 = f2bf(v.w);
        unsigned short l0 = f2bf(v.x - bf2f(h0)), l1 = f2bf(v.y - bf2f(h1));
        unsigned short l2 = f2bf(v.z - bf2f(h2)), l3 = f2bf(v.w - bf2f(h3));
        int off = swz(r, c4 * 8);
        *(unsigned long long*)((char*)aHi + off) = pack4(h0, h1, h2, h3);
        *(unsigned long long*)((char*)aLo + off) = pack4(l0, l1, l2, l3);
    }
    __syncthreads();

    bf16x8 bfr[4][2];
#pragma unroll
    for (int nt = 0; nt < 4; ++nt)
#pragma unroll
        for (int kh = 0; kh < 2; ++kh)
            bfr[nt][kh] = *(const bf16x8*)(Wt +
                ((c * D + nt * 16 + (l & 15)) * D + kh * 32 + (l >> 4) * 8));

    bf16x8 ah[2], al[2];
#pragma unroll
    for (int kh = 0; kh < 2; ++kh) {
        int off = swz(l & 15, kh * 64 + (l >> 4) * 16);
        ah[kh] = *(const bf16x8*)((const char*)aHi + off);
        al[kh] = *(const bf16x8*)((const char*)aLo + off);
    }
    f32x4 acc[4] = {};
#pragma unroll
    for (int nt = 0; nt < 4; ++nt) {
        acc[nt] = __builtin_amdgcn_mfma_f32_16x16x32_bf16(ah[0], bfr[nt][0], acc[nt], 0, 0, 0);
        acc[nt] = __builtin_amdgcn_mfma_f32_16x16x32_bf16(ah[1], bfr[nt][1], acc[nt], 0, 0, 0);
        acc[nt] = __builtin_amdgcn_mfma_f32_16x16x32_bf16(al[0], bfr[nt][0], acc[nt], 0, 0, 0);
        acc[nt] = __builtin_amdgcn_mfma_f32_16x16x32_bf16(al[1], bfr[nt][1], acc[nt], 0, 0, 0);
    }
#pragma unroll
    for (int nt = 0; nt < 4; ++nt)
#pragma unroll
        for (int q = 0; q < 4; ++q)
            part[c][((l >> 4) * 4 + q) * D + nt * 16 + (l & 15)] = acc[nt][q];
    __syncthreads();
#pragma unroll
    for (int cc = 0; cc < 4; ++cc) {
        float4 v = ((const float4*)part[cc])[tid];
        *(float4*)(y + ((size_t)cc * nrows + row0) * D + tid * 4) = v;
    }
}

// ====== cell: out[n] = bbar + 0.25*sum_c sc_c(n)*( sum_e y_c[src_e] + (h[n]-mu)@W_c )
__global__ void __launch_bounds__(256) cell_fused(const float* __restrict__ h,
        const float* __restrict__ y, const int* __restrict__ ptr,
        const int* __restrict__ col, const unsigned short* __restrict__ Wt,
        const float* __restrict__ bias, const float* __restrict__ mu,
        float* __restrict__ out) {
    __shared__ unsigned short aHi[16 * D], aLo[16 * D];
    __shared__ float gbuf[4][16 * D];
    __shared__ int pl[4][17];
    __shared__ float sc[4][16];
    const int tid = threadIdx.x, c = tid >> 6, l = tid & 63;
    const int row0 = blockIdx.x * 16;

    if (tid < 4 * 17) {
        int cc = tid / 17, i = tid % 17;
        pl[cc][i] = ptr[(size_t)cc * N_CELL + row0 + i];
    }
    {
        int r = tid >> 4, c4 = tid & 15;
        float4 v = *(const float4*)(h + (size_t)(row0 + r) * D + c4 * 4);
        if (mu) {
            float4 m = ((const float4*)mu)[c4];
            v.x -= m.x; v.y -= m.y; v.z -= m.z; v.w -= m.w;
        }
        unsigned short h0 = f2bf(v.x), h1 = f2bf(v.y), h2 = f2bf(v.z), h3 = f2bf(v.w);
        unsigned short l0 = f2bf(v.x - bf2f(h0)), l1 = f2bf(v.y - bf2f(h1));
        unsigned short l2 = f2bf(v.z - bf2f(h2)), l3 = f2bf(v.w - bf2f(h3));
        int off = swz(r, c4 * 8);
        *(unsigned long long*)((char*)aHi + off) = pack4(h0, h1, h2, h3);
        *(unsigned long long*)((char*)aLo + off) = pack4(l0, l1, l2, l3);
    }
    __syncthreads();

    if (l < 16) sc[c][l] = 1.0f / (float)(pl[c][l + 1] - pl[c][l] + 1);

    bf16x8 bfr[4][2];
#pragma unroll
    for (int nt = 0; nt < 4; ++nt)
#pragma unroll
        for (int kh = 0; kh < 2; ++kh)
            bfr[nt][kh] = *(const bf16x8*)(Wt +
                ((c * D + nt * 16 + (l & 15)) * D + kh * 32 + (l >> 4) * 8));

    // gather (exact f32): gbuf[c][r][lane] = sum_e y_c[src_e][lane]
    for (int r = 0; r < 16; ++r) {
        int p0 = pl[c][r], p1 = pl[c][r + 1];
        float g = 0.f;
        for (int e = p0; e < p1; ++e)
            g += y[((size_t)c * N_RID + col[e]) * D + l];
        gbuf[c][r * D + l] = g;
    }

    bf16x8 ah[2], al[2];
#pragma unroll
    for (int kh = 0; kh < 2; ++kh) {
        int off = swz(l & 15, kh * 64 + (l >> 4) * 16);
        ah[kh] = *(const bf16x8*)((const char*)aHi + off);
        al[kh] = *(const bf16x8*)((const char*)aLo + off);
    }
    f32x4 acc[4] = {};
#pragma unroll
    for (int nt = 0; nt < 4; ++nt) {
        acc[nt] = __builtin_amdgcn_mfma_f32_16x16x32_bf16(ah[0], bfr[nt][0], acc[nt], 0, 0, 0);
        acc[nt] = __builtin_amdgcn_mfma_f32_16x16x32_bf16(ah[1], bfr[nt][1], acc[nt], 0, 0, 0);
        acc[nt] = __builtin_amdgcn_mfma_f32_16x16x32_bf16(al[0], bfr[nt][0], acc[nt], 0, 0, 0);
        acc[nt] = __builtin_amdgcn_mfma_f32_16x16x32_bf16(al[1], bfr[nt][1], acc[nt], 0, 0, 0);
    }
    // wave-local epilogue: gbuf[c] = sc*(acc + gbuf[c])
#pragma unroll
    for (int nt = 0; nt < 4; ++nt)
#pragma unroll
        for (int q = 0; q < 4; ++q) {
            int row = (l >> 4) * 4 + q, cj = nt * 16 + (l & 15);
            gbuf[c][row * D + cj] = sc[c][row] * (acc[nt][q] + gbuf[c][row * D + cj]);
        }
    __syncthreads();
    for (int i = tid; i < 16 * D; i += 256) {
        int j = i & 63;
        float b = 0.25f * (bias[j] + bias[64 + j] + bias[128 + j] + bias[192 + j]);
        out[(size_t)row0 * D + i] =
            0.25f * (gbuf[0][i] + gbuf[1][i] + gbuf[2][i] + gbuf[3][i]) + b;
    }
}

// == rid: out[n] = bbar + 0.25*sum_c sc_c(n)*((sum_e hs[src_e] - dg*mu_s + h[n]-mu_d)@W_c)
__global__ void __launch_bounds__(256) rid_fused(const float* __restrict__ h,
        const float* __restrict__ hs, const int* __restrict__ ptr,
        const int* __restrict__ col, const unsigned short* __restrict__ Wt,
        const float* __restrict__ bias, const float* __restrict__ mu_d,
        const float* __restrict__ mu_s, float* __restrict__ out) {
    __shared__ unsigned char abuf[4][4096];   // per c: [0,2048)=aHi, [2048,4096)=aLo; reused as part
    __shared__ int pl[4][17];
    __shared__ float sc[4][16];
    const int tid = threadIdx.x, c = tid >> 6, l = tid & 63;
    const int row0 = blockIdx.x * 16;

    if (tid < 4 * 17) {
        int cc = tid / 17, i = tid % 17;
        pl[cc][i] = ptr[(size_t)cc * N_RID + row0 + i];
    }
    __syncthreads();
    if (l < 16) sc[c][l] = 1.0f / (float)(pl[c][l + 1] - pl[c][l] + 1);

    unsigned short* aHi_c = (unsigned short*)abuf[c];
    unsigned short* aLo_c = aHi_c + 1024;
    float muk = mu_s ? mu_s[l] : 0.f;
    float mud = mu_d ? mu_d[l] : 0.f;

    bf16x8 bfr[4][2];
#pragma unroll
    for (int nt = 0; nt < 4; ++nt)
#pragma unroll
        for (int kh = 0; kh < 2; ++kh)
            bfr[nt][kh] = *(const bf16x8*)(Wt +
                ((c * D + nt * 16 + (l & 15)) * D + kh * 32 + (l >> 4) * 8));

    // gather + combine + bf16-split A build (wave-local tile)
    for (int r = 0; r < 16; ++r) {
        int p0 = pl[c][r], p1 = pl[c][r + 1];
        float g = 0.f;
        for (int e = p0; e < p1; ++e)
            g += hs[(size_t)col[e] * D + l];
        float val = g - (float)(p1 - p0) * muk + h[(size_t)(row0 + r) * D + l] - mud;
        unsigned short hi = f2bf(val), lo = f2bf(val - bf2f(hi));
        int off = swz(r, l * 2);
        *(unsigned short*)((char*)aHi_c + off) = hi;
        *(unsigned short*)((char*)aLo_c + off) = lo;
    }

    bf16x8 ah[2], al[2];
#pragma unroll
    for (int kh = 0; kh < 2; ++kh) {
        int off = swz(l & 15, kh * 64 + (l >> 4) * 16);
        ah[kh] = *(const bf16x8*)((const char*)aHi_c + off);
        al[kh] = *(const bf16x8*)((const char*)aLo_c + off);
    }
    f32x4 acc[4] = {};
#pragma unroll
    for (int nt = 0; nt < 4; ++nt) {
        acc[nt] = __builtin_amdgcn_mfma_f32_16x16x32_bf16(ah[0], bfr[nt][0], acc[nt], 0, 0, 0);
        acc[nt] = __builtin_amdgcn_mfma_f32_16x16x32_bf16(ah[1], bfr[nt][1], acc[nt], 0, 0, 0);
        acc[nt] = __builtin_amdgcn_mfma_f32_16x16x32_bf16(al[0], bfr[nt][0], acc[nt], 0, 0, 0);
        acc[nt] = __builtin_amdgcn_mfma_f32_16x16x32_bf16(al[1], bfr[nt][1], acc[nt], 0, 0, 0);
    }
    float* part_c = (float*)abuf[c];          // overlay own A tile (dead after MFMA)
#pragma unroll
    for (int nt = 0; nt < 4; ++nt)
#pragma unroll
        for (int q = 0; q < 4; ++q) {
            int row = (l >> 4) * 4 + q, cj = nt * 16 + (l & 15);
            part_c[row * D + cj] = sc[c][row] * acc[nt][q];
        }
    __syncthreads();
    for (int i = tid; i < 16 * D; i += 256) {
        int j = i & 63;
        float b = 0.25f * (bias[j] + bias[64 + j] + bias[128 + j] + bias[192 + j]);
        out[(size_t)row0 * D + i] =
            0.25f * (((float*)abuf[0])[i] + ((float*)abuf[1])[i] +
                     ((float*)abuf[2])[i] + ((float*)abuf[3])[i]) + b;
    }
}

// ------------------------- column sums (for centering)
__global__ void colsum(const float* __restrict__ x, float* __restrict__ sum, int nrows) {
    __shared__ float p[4][64];
    int j = threadIdx.x & 63, rl = threadIdx.x >> 6;
    float local = 0.f;
    for (int r = blockIdx.x * 4 + rl; r < nrows; r += gridDim.x * 4)
        local += x[(size_t)r * D + j];
    p[rl][j] = local;
    __syncthreads();
    if (rl == 0) atomicAdd(&sum[j], p[0][j] + p[1][j] + p[2][j] + p[3][j]);
}

__global__ void finalize_mean(float* __restrict__ s, float inv_n) {
    s[threadIdx.x] *= inv_n;
}

__global__ void final_combine(float* __restrict__ out, const float* __restrict__ rid,
        const float* __restrict__ mu_c, const float* __restrict__ mu_r) {
    int t = blockIdx.x * 256 + threadIdx.x;
    if (t >= N_CELL * D) return;
    int row = t >> 6, j = t & 63;
    float v = (row < N_RID) ? (rid[(size_t)row * D + j] - mu_r[j])
                            : (out[t] - mu_c[j]);
    out[t] = fmaxf(v, 0.0f);
}

extern "C" void kernel_launch(void* const* d_in, const int* in_sizes, int n_in,
                              void* d_out, int out_size, void* d_ws, size_t ws_size,
                              hipStream_t stream) {
    const float* x_rid  = (const float*)d_in[0];
    const float* x_cell = (const float*)d_in[1];
    const int* dst_fwd  = (const int*)d_in[3];
    const int* src_fwd  = (const int*)d_in[2];
    const int* src_rev  = (const int*)d_in[4];
    const int* dst_rev  = (const int*)d_in[5];
    const float* W1f = (const float*)d_in[6];
    const float* b1f = (const float*)d_in[7];
    const float* W1r = (const float*)d_in[8];
    const float* b1r = (const float*)d_in[9];
    const float* W2f = (const float*)d_in[10];
    const float* b2f = (const float*)d_in[11];
    const float* W2r = (const float*)d_in[12];
    const float* b2r = (const float*)d_in[13];
    float* out = (float*)d_out;

    float* ws    = (float*)d_ws;
    float* rid1  = ws;
    float* cell1 = rid1  + (size_t)N_RID * D;
    float* rid2  = cell1 + (size_t)N_CELL * D;
    float* y     = rid2  + (size_t)N_RID * D;
    float* sums  = y     + (size_t)NCOLS * N_RID * D;
    int*   ptrF  = (int*)(sums + 256);
    int*   colF  = ptrF + (size_t)NCOLS * N_CELL + 1;
    int*   ptrR  = colF + TOTE;
    int*   colR  = ptrR + (size_t)NCOLS * N_RID + 1;
    uintptr_t wp = ((uintptr_t)(colR + TOTE) + 15) & ~(uintptr_t)15;
    unsigned short* Wt1f = (unsigned short*)wp;
    unsigned short* Wt1r = Wt1f + NCOLS * D * D;
    unsigned short* Wt2f = Wt1r + NCOLS * D * D;
    unsigned short* Wt2r = Wt2f + NCOLS * D * D;
    // build-phase overlays inside rid2 region (dead until layer 2)
    int*   cntF  = (int*)rid2;
    int*   cntR  = cntF + (size_t)NCOLS * N_CELL;
    int*   csumF = cntR + (size_t)NCOLS * N_RID;
    int*   csumR = csumF + 2048;

    const int NBF = NCOLS * N_CELL;
    const int NBR = NCOLS * N_RID;
    const int g_edges = (TOTE + 255) / 256;

    hipMemsetAsync(cntF, 0, (size_t)NBF * sizeof(int), stream);
    hipMemsetAsync(cntR, 0, (size_t)NBR * sizeof(int), stream);
    hipMemsetAsync(sums, 0, 256 * sizeof(float), stream);

    prep_w<<<(NCOLS * D * D + 255) / 256, 256, 0, stream>>>(W1f, W1r, W2f, W2r,
                                                            Wt1f, Wt1r, Wt2f, Wt2r);

    hist_kernel<<<g_edges, 256, 0, stream>>>(dst_fwd, cntF, N_CELL);
    hist_kernel<<<g_edges, 256, 0, stream>>>(dst_rev, cntR, N_RID);
    int nchF = (NBF + 1023) / 1024, nchR = (NBR + 1023) / 1024;
    scan1<<<nchF, 256, 0, stream>>>(cntF, ptrF, csumF, NBF);
    scan2<<<1, 256, 0, stream>>>(csumF, nchF);
    scan3<<<(NBF + 255) / 256, 256, 0, stream>>>(ptrF, csumF, NBF);
    scan1<<<nchR, 256, 0, stream>>>(cntR, ptrR, csumR, NBR);
    scan2<<<1, 256, 0, stream>>>(csumR, nchR);
    scan3<<<(NBR + 255) / 256, 256, 0, stream>>>(ptrR, csumR, NBR);
    set_sentinels<<<1, 64, 0, stream>>>(ptrF, ptrR);
    fill_kernel<<<g_edges, 256, 0, stream>>>(dst_fwd, src_fwd, ptrF, cntF, colF, N_CELL);
    fill_kernel<<<g_edges, 256, 0, stream>>>(dst_rev, src_rev, ptrR, cntR, colR, N_RID);

    // ---------------- layer 1 ----------------
    y_gemm<<<N_RID / 16, 256, 0, stream>>>(x_rid, Wt1f, nullptr, y, N_RID);
    cell_fused<<<N_CELL / 16, 256, 0, stream>>>(x_cell, y, ptrF, colF, Wt1f, b1f,
                                                nullptr, cell1);
    rid_fused<<<N_RID / 16, 256, 0, stream>>>(x_rid, x_cell, ptrR, colR, Wt1r, b1r,
                                              nullptr, nullptr, rid1);
    colsum<<<1024, 256, 0, stream>>>(cell1, sums + 0, N_CELL);
    colsum<<<1024, 256, 0, stream>>>(rid1, sums + 64, N_RID);
    finalize_mean<<<1, 64, 0, stream>>>(sums + 0, 1.0f / N_CELL);
    finalize_mean<<<1, 64, 0, stream>>>(sums + 64, 1.0f / N_RID);

    // ---------------- layer 2 ----------------
    y_gemm<<<N_RID / 16, 256, 0, stream>>>(rid1, Wt2f, sums + 64, y, N_RID);
    cell_fused<<<N_CELL / 16, 256, 0, stream>>>(cell1, y, ptrF, colF, Wt2f, b2f,
                                                sums + 0, out);
    rid_fused<<<N_RID / 16, 256, 0, stream>>>(rid1, cell1, ptrR, colR, Wt2r, b2r,
                                              sums + 64, sums + 0, rid2);
    colsum<<<1024, 256, 0, stream>>>(out, sums + 128, N_CELL);
    colsum<<<1024, 256, 0, stream>>>(rid2, sums + 192, N_RID);
    finalize_mean<<<1, 64, 0, stream>>>(sums + 128, 1.0f / N_CELL);
    finalize_mean<<<1, 64, 0, stream>>>(sums + 192, 1.0f / N_RID);

    final_combine<<<(N_CELL * D) / 256, 256, 0, stream>>>(out, rid2, sums + 128,
                                                          sums + 192);
}